// Round 1
// 259.638 us; speedup vs baseline: 1.1222x; 1.1222x over previous
//
#include <hip/hip_runtime.h>
#include <stdint.h>

// BitLinear via i8 MFMA, round 5.
//
// Changes vs round 4 (291 us total = ~159 GEMM + ~130 unpack):
//  1. GEMM: 256x256 tile, 8 waves (512 thr), double-buffered LDS (2 x 64 KB),
//     ONE barrier per 128-B K-step, next tile's global_load_lds issued BEFORE
//     computing the current tile (T3-minimum pipeline), s_setprio(1) around
//     each 8-MFMA cluster (T5). Fragment-blocked layout unchanged ->
//     staging stays 1-KB-contiguous global_load_lds, ds_reads conflict-free.
//  2. Unpack: each thread handles a full 128-B k-chunk of one row: reads
//     64 CONTIGUOUS bytes (4 x dwordx4 in flight), expands bits via the
//     multiply-spread trick (bit j -> byte j via *0x204081, then
//     ~(spread*0xFE) gives 1->0x01 / 0->0xFF per byte, carry-free).
//     Same blocked output layout as the verified round-4 kernel.
//
// Blocked layout (unchanged): byte (m,k) ->
//   ((g*32+c)*4096) + s*1024 + half*512 + r*16 + b
//   g=m>>5, r=m&31, c=k>>7, s=(k>>5)&3, half=(k>>4)&1, b=k&15
// One 1-KB block (g,c,s) = one 32x32 i8 MFMA fragment in lane order.

typedef int v4i  __attribute__((ext_vector_type(4)));
typedef int v16i __attribute__((ext_vector_type(16)));

#define BATCH 8192
#define OUTF  4096
#define KDIM  4096
#define BM    256
#define BN    256
#define BKB   128
#define NSTEP (KDIM / BKB)   // 32

// ---------------- unpack: packed bits -> +/-1 int8, blocked layout ----------
// x holds 8 valid bits. byte j of pl = (bit j) ? 0x01 : 0xFF, ph = bits 4..7.
__device__ __forceinline__ void expand_word(uint32_t x, uint32_t& pl, uint32_t& ph) {
    uint32_t lo = ((x & 0xFu) * 0x204081u) & 0x01010101u;          // bit j -> byte j
    uint32_t hi = (((x >> 4) & 0xFu) * 0x204081u) & 0x01010101u;
    pl = ~((lo << 8) - (lo << 1));   // ~(lo*0xFE): 1 -> 0x01, 0 -> 0xFF per byte
    ph = ~((hi << 8) - (hi << 1));
}

__global__ __launch_bounds__(256) void unpack_kernel(const int* __restrict__ a_packed,
                                                     const int* __restrict__ w_packed,
                                                     char* __restrict__ Ai8,
                                                     char* __restrict__ Wi8) {
    const int A_WORK = BATCH * 32;               // one thread per (row, 128-B chunk)
    int t = blockIdx.x * 256 + threadIdx.x;
    const int* __restrict__ src = a_packed;
    int4* dst = (int4*)Ai8;
    if (t >= A_WORK) { t -= A_WORK; src = w_packed; dst = (int4*)Wi8; }

    const int r = t & 31;          // row within group (lanes 0..31 -> coalesced writes)
    const int c = (t >> 5) & 31;   // 128-B k-chunk
    const int g = t >> 10;         // row group
    const int m = g * 32 + r;

    // 64 contiguous bytes: words m*512 + c*16 .. +15  (4 x global_load_dwordx4)
    const int4* s4 = (const int4*)src + (m * 128 + c * 4);
    int4 v0 = s4[0], v1 = s4[1], v2 = s4[2], v3 = s4[3];

    int4* dbase = dst + ((g * 32 + c) * 256 + r);

#define EMIT(S, V)                                                     \
    {                                                                  \
        uint32_t l0, h0, l1, h1, l2, h2, l3, h3;                       \
        expand_word((uint32_t)(V).x, l0, h0);                          \
        expand_word((uint32_t)(V).y, l1, h1);                          \
        expand_word((uint32_t)(V).z, l2, h2);                          \
        expand_word((uint32_t)(V).w, l3, h3);                          \
        int4 o0 = make_int4((int)l0, (int)h0, (int)l1, (int)h1);       \
        int4 o1 = make_int4((int)l2, (int)h2, (int)l3, (int)h3);       \
        dbase[(S) * 64]      = o0;  /* half 0 */                       \
        dbase[(S) * 64 + 32] = o1;  /* half 1 */                       \
    }
    EMIT(0, v0) EMIT(1, v1) EMIT(2, v2) EMIT(3, v3)
#undef EMIT
}

// ---------------- i8 MFMA GEMM: 256x256 tile, 8 waves, dbuf LDS ------------
__global__ __launch_bounds__(512, 2) void bitgemm_mfma(const char* __restrict__ A,
                                                       const char* __restrict__ W,
                                                       const float* __restrict__ bias,
                                                       float* __restrict__ out) {
    // Per buffer: A blocks 0..31 (g*4+s), W blocks 32..63 ((g2)*4+s). 64 KB x 2.
    __shared__ __attribute__((aligned(16))) char lds[2 * 65536];

    const int tid  = threadIdx.x;
    const int lane = tid & 63;
    const int w    = __builtin_amdgcn_readfirstlane(tid >> 6);  // 0..7
    const int wr   = w >> 2;   // wave M row: 0..1  (128 rows each)
    const int wc   = w & 3;    // wave N col: 0..3  (64 cols each)
    const int bx   = blockIdx.x;   // N: 16 blocks
    const int by   = blockIdx.y;   // M: 32 blocks

    // group stride in blocked layout = 32 chunks * 4096 B = 131072 B
    const char* baseA = A + (size_t)by * 8 * 131072 + (size_t)lane * 16;
    const char* baseW = W + (size_t)bx * 8 * 131072 + (size_t)lane * 16;

    v16i acc[4][2];
#pragma unroll
    for (int mt = 0; mt < 4; ++mt)
#pragma unroll
        for (int nt = 0; nt < 2; ++nt)
#pragma unroll
            for (int rg = 0; rg < 16; ++rg) acc[mt][nt][rg] = 0;

    // wave w stages fragment blocks w*8 .. w*8+7 (1 KB contiguous each)
    auto stage = [&](int kc, int buf) {
        char* ldst = lds + buf * 65536;
#pragma unroll
        for (int j = 0; j < 8; ++j) {
            const int bi = w * 8 + j;
            const char* g;
            if (bi < 32) {
                g = baseA + (bi >> 2) * 131072 + (bi & 3) * 1024 + kc * 4096;
            } else {
                const int b2 = bi - 32;
                g = baseW + (b2 >> 2) * 131072 + (b2 & 3) * 1024 + kc * 4096;
            }
            __builtin_amdgcn_global_load_lds(
                (const __attribute__((address_space(1))) void*)g,
                (__attribute__((address_space(3))) void*)(ldst + bi * 1024),
                16, 0, 0);
        }
    };

    // per-wave LDS read bases: A frag (mt,s) at aoff + (mt*4+s)*1024,
    //                          W frag (nt,s) at woff + (nt*4+s)*1024
    const int aoff = wr * 16384 + lane * 16;
    const int woff = 32768 + wc * 8192 + lane * 16;

    stage(0, 0);
    int cur = 0;
#pragma unroll 1
    for (int kc = 0; kc < NSTEP; ++kc) {
        // drain own vmcnt (tile kc loads, issued one full compute phase ago),
        // drain lgkm (reads of buf cur^1 finished), barrier -> buf[cur] ready,
        // buf[cur^1] free to overwrite.
        __syncthreads();
        if (kc < NSTEP - 1) stage(kc + 1, cur ^ 1);   // flies under the MFMAs below

        const char* ldsC = lds + cur * 65536;
#pragma unroll
        for (int s = 0; s < 4; ++s) {
            v4i av[4], wv[2];
#pragma unroll
            for (int mt = 0; mt < 4; ++mt)
                av[mt] = *(const v4i*)(ldsC + aoff + (mt * 4 + s) * 1024);
#pragma unroll
            for (int nt = 0; nt < 2; ++nt)
                wv[nt] = *(const v4i*)(ldsC + woff + (nt * 4 + s) * 1024);
            __builtin_amdgcn_s_setprio(1);
#pragma unroll
            for (int mt = 0; mt < 4; ++mt)
#pragma unroll
                for (int nt = 0; nt < 2; ++nt)
                    acc[mt][nt] = __builtin_amdgcn_mfma_i32_32x32x32_i8(
                        av[mt], wv[nt], acc[mt][nt], 0, 0, 0);
            __builtin_amdgcn_s_setprio(0);
        }
        cur ^= 1;
    }

    // Epilogue. C/D layout (32x32, HW-verified): col=lane&31,
    // row=(reg&3)+8*(reg>>2)+4*(lane>>5).
    const int cl = lane & 31;
    const int r0 = (lane >> 5) * 4;
    const int m0 = by * BM;
    const int n0 = bx * BN;
#pragma unroll
    for (int mt = 0; mt < 4; ++mt) {
        const int rowbase = m0 + (wr * 4 + mt) * 32 + r0;
#pragma unroll
        for (int nt = 0; nt < 2; ++nt) {
            const int col = n0 + (wc * 2 + nt) * 32 + cl;
            const float bv = bias[col];
#pragma unroll
            for (int rg = 0; rg < 16; ++rg) {
                const int row = rowbase + (rg & 3) + 8 * (rg >> 2);
                out[(size_t)row * OUTF + col] = (float)acc[mt][nt][rg] + bv;
            }
        }
    }
}

extern "C" void kernel_launch(void* const* d_in, const int* in_sizes, int n_in,
                              void* d_out, int out_size, void* d_ws, size_t ws_size,
                              hipStream_t stream) {
    const int*   a_packed = (const int*)d_in[0];    // [8192, 512]
    const int*   w_packed = (const int*)d_in[1];    // [4096, 512]
    const float* bias     = (const float*)d_in[2];  // [4096]
    float*       out      = (float*)d_out;          // [8192, 4096]

    char* Ai8 = (char*)d_ws;                         // 32 MiB blocked
    char* Wi8 = Ai8 + (size_t)BATCH * KDIM;          // 16 MiB blocked

    const int total = (BATCH + OUTF) * 32;           // 393,216 threads
    unpack_kernel<<<total / 256, 256, 0, stream>>>(a_packed, w_packed, Ai8, Wi8);

    dim3 grid(OUTF / BN, BATCH / BM);   // (16, 32)
    bitgemm_mfma<<<grid, 512, 0, stream>>>(Ai8, Wi8, bias, out);
}